// Round 4
// baseline (144.521 us; speedup 1.0000x reference)
//
#include <hip/hip_runtime.h>

// GIoU loss, N=4M boxes, [N,4] f32 -> one float4 per box (16B/lane coalesced).
// 128 MB read/call, ~50% L3-resident (FETCH_SIZE==62.5 MB every round).
// R1: 67us (no ILP). R2: 42.5us (8 loads in flight, grid-starved, occ 31%).
// R3: 42.3us (occ 59% but launch_bounds(256,8) -> 28 VGPR, loads serialized).
// R2 vs R3: ILP<->TLP trade at identical 42us => neither is the limiter, or
// the drain-every-iteration pattern caps in-flight depth.
// R4: max concurrency on BOTH axes: 16 independent dwordx4/thread (16KB/wave
// in flight, one-shot, no iteration drain), no VGPR cap, full grid 1954
// blocks (~7.6/CU). If this doesn't move, ~3 TB/s is the path ceiling.

#define TPB         256
#define PER_THREAD  8
#define CHUNK       (TPB * PER_THREAD)   // 2048 boxes per block

__device__ __forceinline__ float giou_term(float4 p, float4 t) {
    float area_p = (p.z - p.x) * (p.w - p.y);
    float area_t = (t.z - t.x) * (t.w - t.y);
    float iw = fmaxf(fminf(p.z, t.z) - fmaxf(p.x, t.x), 0.0f);
    float ih = fmaxf(fminf(p.w, t.w) - fmaxf(p.y, t.y), 0.0f);
    float inter = iw * ih;
    float uni   = area_p + area_t - inter;
    float iou   = inter / uni;
    float cw = fmaxf(p.z, t.z) - fminf(p.x, t.x);
    float ch = fmaxf(p.w, t.w) - fminf(p.y, t.y);
    float area_c = cw * ch;
    return 1.0f - (iou - (area_c - uni) / area_c);
}

__global__ void giou_main_kernel(
        const float4* __restrict__ pred,
        const float4* __restrict__ targ,
        float* __restrict__ partials,
        int n) {
    const int base = blockIdx.x * CHUNK;
    const int i0   = base + threadIdx.x;
    float sum = 0.0f;

    if (base + CHUNK <= n) {
        // 16 independent dwordx4 loads, all issued before any consumption
        float4 p[PER_THREAD], t[PER_THREAD];
        #pragma unroll
        for (int k = 0; k < PER_THREAD; ++k) p[k] = pred[i0 + k * TPB];
        #pragma unroll
        for (int k = 0; k < PER_THREAD; ++k) t[k] = targ[i0 + k * TPB];
        #pragma unroll
        for (int k = 0; k < PER_THREAD; ++k) sum += giou_term(p[k], t[k]);
    } else {
        #pragma unroll
        for (int k = 0; k < PER_THREAD; ++k) {
            int i = i0 + k * TPB;
            if (i < n) sum += giou_term(pred[i], targ[i]);
        }
    }

    // wave reduce (wave = 64)
    #pragma unroll
    for (int off = 32; off > 0; off >>= 1)
        sum += __shfl_down(sum, off, 64);

    __shared__ float wave_sums[TPB / 64];
    int lane = threadIdx.x & 63;
    int wid  = threadIdx.x >> 6;
    if (lane == 0) wave_sums[wid] = sum;
    __syncthreads();
    if (threadIdx.x == 0) {
        partials[blockIdx.x] = wave_sums[0] + wave_sums[1]
                             + wave_sums[2] + wave_sums[3];
    }
}

__global__ __launch_bounds__(TPB) void giou_finalize_kernel(
        const float* __restrict__ partials, int nblocks,
        float* __restrict__ out, double inv_n) {
    double s = 0.0;
    for (int i = threadIdx.x; i < nblocks; i += TPB)
        s += (double)partials[i];
    #pragma unroll
    for (int off = 32; off > 0; off >>= 1)
        s += __shfl_down(s, off, 64);
    __shared__ double wave_sums[TPB / 64];
    int lane = threadIdx.x & 63;
    int wid  = threadIdx.x >> 6;
    if (lane == 0) wave_sums[wid] = s;
    __syncthreads();
    if (threadIdx.x == 0) {
        double tot = wave_sums[0] + wave_sums[1] + wave_sums[2] + wave_sums[3];
        *out = (float)(tot * inv_n);
    }
}

extern "C" void kernel_launch(void* const* d_in, const int* in_sizes, int n_in,
                              void* d_out, int out_size, void* d_ws, size_t ws_size,
                              hipStream_t stream) {
    const float4* pred = (const float4*)d_in[0];
    const float4* targ = (const float4*)d_in[1];
    float* out      = (float*)d_out;
    float* partials = (float*)d_ws;          // nblocks floats, all written
    int n = in_sizes[0] / 4;                 // 4,000,000 boxes
    int nblocks = (n + CHUNK - 1) / CHUNK;   // 1954

    giou_main_kernel<<<nblocks, TPB, 0, stream>>>(pred, targ, partials, n);
    giou_finalize_kernel<<<1, TPB, 0, stream>>>(partials, nblocks, out,
                                                1.0 / (double)n);
}

// Round 6
// 135.994 us; speedup vs baseline: 1.0627x; 1.0627x over previous
//
#include <hip/hip_runtime.h>

// GIoU loss, N=4M boxes, [N,4] f32 -> one float4 per box (16B/lane coalesced).
// 128 MB read/call. R2/R3/R4 all pinned at 42.5us = 3.0 TB/s effective read
// across wildly different ILP/TLP points => concurrency is not the limiter.
// Observation: 3.0 TB/s == the read half of the 6.3 TB/s copy ceiling.
// R6 (retry of R5): nontemporal loads via clang ext_vector_type (the HIP
// float4 class is rejected by the builtin). If dur drops -> IF$ retention
// was the limiter. If unchanged w/ FETCH_SIZE ~128MB -> structural read
// ceiling; declare roofline. If regression -> IF$ load-bearing; revert.

#define TPB         256
#define PER_THREAD  8
#define CHUNK       (TPB * PER_THREAD)   // 2048 boxes per block

typedef float vfloat4 __attribute__((ext_vector_type(4)));

__device__ __forceinline__ vfloat4 nt_load(const vfloat4* p) {
    return __builtin_nontemporal_load(p);
}

__device__ __forceinline__ float giou_term(vfloat4 p, vfloat4 t) {
    // p = {x1,y1,x2,y2}
    float area_p = (p.z - p.x) * (p.w - p.y);
    float area_t = (t.z - t.x) * (t.w - t.y);
    float iw = fmaxf(fminf(p.z, t.z) - fmaxf(p.x, t.x), 0.0f);
    float ih = fmaxf(fminf(p.w, t.w) - fmaxf(p.y, t.y), 0.0f);
    float inter = iw * ih;
    float uni   = area_p + area_t - inter;
    float iou   = inter / uni;
    float cw = fmaxf(p.z, t.z) - fminf(p.x, t.x);
    float ch = fmaxf(p.w, t.w) - fminf(p.y, t.y);
    float area_c = cw * ch;
    return 1.0f - (iou - (area_c - uni) / area_c);
}

__global__ void giou_main_kernel(
        const vfloat4* __restrict__ pred,
        const vfloat4* __restrict__ targ,
        float* __restrict__ partials,
        int n) {
    const int base = blockIdx.x * CHUNK;
    const int i0   = base + threadIdx.x;
    float sum = 0.0f;

    if (base + CHUNK <= n) {
        vfloat4 p[PER_THREAD], t[PER_THREAD];
        #pragma unroll
        for (int k = 0; k < PER_THREAD; ++k) p[k] = nt_load(&pred[i0 + k * TPB]);
        #pragma unroll
        for (int k = 0; k < PER_THREAD; ++k) t[k] = nt_load(&targ[i0 + k * TPB]);
        #pragma unroll
        for (int k = 0; k < PER_THREAD; ++k) sum += giou_term(p[k], t[k]);
    } else {
        #pragma unroll
        for (int k = 0; k < PER_THREAD; ++k) {
            int i = i0 + k * TPB;
            if (i < n) sum += giou_term(nt_load(&pred[i]), nt_load(&targ[i]));
        }
    }

    // wave reduce (wave = 64)
    #pragma unroll
    for (int off = 32; off > 0; off >>= 1)
        sum += __shfl_down(sum, off, 64);

    __shared__ float wave_sums[TPB / 64];
    int lane = threadIdx.x & 63;
    int wid  = threadIdx.x >> 6;
    if (lane == 0) wave_sums[wid] = sum;
    __syncthreads();
    if (threadIdx.x == 0) {
        partials[blockIdx.x] = wave_sums[0] + wave_sums[1]
                             + wave_sums[2] + wave_sums[3];
    }
}

__global__ __launch_bounds__(TPB) void giou_finalize_kernel(
        const float* __restrict__ partials, int nblocks,
        float* __restrict__ out, double inv_n) {
    double s = 0.0;
    for (int i = threadIdx.x; i < nblocks; i += TPB)
        s += (double)partials[i];
    #pragma unroll
    for (int off = 32; off > 0; off >>= 1)
        s += __shfl_down(s, off, 64);
    __shared__ double wave_sums[TPB / 64];
    int lane = threadIdx.x & 63;
    int wid  = threadIdx.x >> 6;
    if (lane == 0) wave_sums[wid] = s;
    __syncthreads();
    if (threadIdx.x == 0) {
        double tot = wave_sums[0] + wave_sums[1] + wave_sums[2] + wave_sums[3];
        *out = (float)(tot * inv_n);
    }
}

extern "C" void kernel_launch(void* const* d_in, const int* in_sizes, int n_in,
                              void* d_out, int out_size, void* d_ws, size_t ws_size,
                              hipStream_t stream) {
    const vfloat4* pred = (const vfloat4*)d_in[0];
    const vfloat4* targ = (const vfloat4*)d_in[1];
    float* out      = (float*)d_out;
    float* partials = (float*)d_ws;          // nblocks floats, all written
    int n = in_sizes[0] / 4;                 // 4,000,000 boxes
    int nblocks = (n + CHUNK - 1) / CHUNK;   // 1954

    giou_main_kernel<<<nblocks, TPB, 0, stream>>>(pred, targ, partials, n);
    giou_finalize_kernel<<<1, TPB, 0, stream>>>(partials, nblocks, out,
                                                1.0 / (double)n);
}

// Round 7
// 135.507 us; speedup vs baseline: 1.0665x; 1.0036x over previous
//
#include <hip/hip_runtime.h>

// GIoU loss, N=4M boxes, [N,4] f32 -> one float4 per box (16B/lane coalesced).
// 128 MB read/call.
// R2-R4: pinned at 42.5us = 3.0 TB/s via the IF$-retention read path.
// R6: nontemporal loads -> main kernel dropped out of top-5 (<40.5us, ~34us
//     by subtraction). Harness fill kernel shows 6.6 TB/s is achievable.
// R7: give the register allocator room for all 16 nt loads in flight:
//     __launch_bounds__(256,4) (<=128 VGPR, >=16 waves/CU). R4 showed the
//     default clamps to 32 VGPR, serializing the load queue.

#define TPB         256
#define PER_THREAD  8
#define CHUNK       (TPB * PER_THREAD)   // 2048 boxes per block

typedef float vfloat4 __attribute__((ext_vector_type(4)));

__device__ __forceinline__ vfloat4 nt_load(const vfloat4* p) {
    return __builtin_nontemporal_load(p);
}

__device__ __forceinline__ float giou_term(vfloat4 p, vfloat4 t) {
    // box = {x1,y1,x2,y2}
    float area_p = (p.z - p.x) * (p.w - p.y);
    float area_t = (t.z - t.x) * (t.w - t.y);
    float iw = fmaxf(fminf(p.z, t.z) - fmaxf(p.x, t.x), 0.0f);
    float ih = fmaxf(fminf(p.w, t.w) - fmaxf(p.y, t.y), 0.0f);
    float inter = iw * ih;
    float uni   = area_p + area_t - inter;
    float iou   = inter / uni;
    float cw = fmaxf(p.z, t.z) - fminf(p.x, t.x);
    float ch = fmaxf(p.w, t.w) - fminf(p.y, t.y);
    float area_c = cw * ch;
    return 1.0f - (iou - (area_c - uni) / area_c);
}

__global__ __launch_bounds__(TPB, 4) void giou_main_kernel(
        const vfloat4* __restrict__ pred,
        const vfloat4* __restrict__ targ,
        float* __restrict__ partials,
        int n) {
    const int base = blockIdx.x * CHUNK;
    const int i0   = base + threadIdx.x;
    float sum = 0.0f;

    if (base + CHUNK <= n) {
        // 16 independent nt dwordx4 loads, all issued before any consumption
        vfloat4 p[PER_THREAD], t[PER_THREAD];
        #pragma unroll
        for (int k = 0; k < PER_THREAD; ++k) p[k] = nt_load(&pred[i0 + k * TPB]);
        #pragma unroll
        for (int k = 0; k < PER_THREAD; ++k) t[k] = nt_load(&targ[i0 + k * TPB]);
        #pragma unroll
        for (int k = 0; k < PER_THREAD; ++k) sum += giou_term(p[k], t[k]);
    } else {
        #pragma unroll
        for (int k = 0; k < PER_THREAD; ++k) {
            int i = i0 + k * TPB;
            if (i < n) sum += giou_term(nt_load(&pred[i]), nt_load(&targ[i]));
        }
    }

    // wave reduce (wave = 64)
    #pragma unroll
    for (int off = 32; off > 0; off >>= 1)
        sum += __shfl_down(sum, off, 64);

    __shared__ float wave_sums[TPB / 64];
    int lane = threadIdx.x & 63;
    int wid  = threadIdx.x >> 6;
    if (lane == 0) wave_sums[wid] = sum;
    __syncthreads();
    if (threadIdx.x == 0) {
        partials[blockIdx.x] = wave_sums[0] + wave_sums[1]
                             + wave_sums[2] + wave_sums[3];
    }
}

__global__ __launch_bounds__(TPB) void giou_finalize_kernel(
        const float* __restrict__ partials, int nblocks,
        float* __restrict__ out, double inv_n) {
    double s = 0.0;
    for (int i = threadIdx.x; i < nblocks; i += TPB)
        s += (double)partials[i];
    #pragma unroll
    for (int off = 32; off > 0; off >>= 1)
        s += __shfl_down(s, off, 64);
    __shared__ double wave_sums[TPB / 64];
    int lane = threadIdx.x & 63;
    int wid  = threadIdx.x >> 6;
    if (lane == 0) wave_sums[wid] = s;
    __syncthreads();
    if (threadIdx.x == 0) {
        double tot = wave_sums[0] + wave_sums[1] + wave_sums[2] + wave_sums[3];
        *out = (float)(tot * inv_n);
    }
}

extern "C" void kernel_launch(void* const* d_in, const int* in_sizes, int n_in,
                              void* d_out, int out_size, void* d_ws, size_t ws_size,
                              hipStream_t stream) {
    const vfloat4* pred = (const vfloat4*)d_in[0];
    const vfloat4* targ = (const vfloat4*)d_in[1];
    float* out      = (float*)d_out;
    float* partials = (float*)d_ws;          // nblocks floats, all written
    int n = in_sizes[0] / 4;                 // 4,000,000 boxes
    int nblocks = (n + CHUNK - 1) / CHUNK;   // 1954

    giou_main_kernel<<<nblocks, TPB, 0, stream>>>(pred, targ, partials, n);
    giou_finalize_kernel<<<1, TPB, 0, stream>>>(partials, nblocks, out,
                                                1.0 / (double)n);
}